// Round 1
// baseline (292.690 us; speedup 1.0000x reference)
//
#include <hip/hip_runtime.h>
#include <math.h>

#define B 32
#define T 2048
#define H 512

#define BT2 64             // t rows per k2 block
#define APAD 40            // padded LDS row stride for A (bf16 elems)

typedef __attribute__((ext_vector_type(8))) __bf16 bf16x8;
typedef __attribute__((ext_vector_type(4))) __bf16 bf16x4v;
typedef __attribute__((ext_vector_type(4))) float f32x4;
typedef __attribute__((ext_vector_type(4))) float floatx4;

union pack8 { bf16x4v h; uint2 u; };

static __device__ __forceinline__ void gl_lds16(const void* g, void* l) {
    __builtin_amdgcn_global_load_lds(
        (const __attribute__((address_space(1))) void*)g,
        (__attribute__((address_space(3))) void*)l, 16, 0, 0);
}

// ---------------- K_init: flat grid.
// blocks [0,256): GEMV q-proj (b=blk>>3, s=blk&7)
// blocks [256,288): convert v_w slice -> bf16
// block 288: zero ctx_num (B*H) and denom (B)
__global__ __launch_bounds__(256) void k_init(const float* __restrict__ query,
                                              const float* __restrict__ q_w,
                                              const float* __restrict__ bias,
                                              const float* __restrict__ v_w,
                                              float* __restrict__ qpb,
                                              unsigned short* __restrict__ wbf,
                                              float* __restrict__ ctx_num,
                                              float* __restrict__ denom) {
    const int blk = blockIdx.x;
    const int tid = threadIdx.x;

    if (blk >= 288) {
        // zero accumulators
#pragma unroll
        for (int i = 0; i < 16; ++i) {
            const int off = tid * 4 + i * 1024;
            *(f32x4*)(ctx_num + off) = (f32x4){0.f, 0.f, 0.f, 0.f};
        }
        if (tid < B) denom[tid] = 0.f;
        return;
    }
    if (blk >= 256) {
        const int c = blk - 256;
        const size_t base = (size_t)c * 8192 + tid * 4;
#pragma unroll
        for (int i = 0; i < 8; ++i) {
            const size_t off = base + (size_t)i * 1024;
            f32x4 a = *(const f32x4*)(v_w + off);
            pack8 p;
            p.h = __builtin_convertvector(a, bf16x4v);
            *(uint2*)(wbf + off) = p.u;
        }
        return;
    }

    const int b = blk >> 3;
    const int s = blk & 7;
    const int wave = tid >> 6;
    const int lane = tid & 63;

    const float* qb = query + (size_t)b * H + lane * 8;
    float4 q0 = *(const float4*)qb;
    float4 q1 = *(const float4*)(qb + 4);

    const int o0 = s * 64 + wave * 16;
#pragma unroll
    for (int i = 0; i < 16; ++i) {
        const int o = o0 + i;
        const float* wr = q_w + (size_t)o * H + lane * 8;
        float4 w0 = *(const float4*)wr;
        float4 w1 = *(const float4*)(wr + 4);
        float acc = w0.x * q0.x + w0.y * q0.y + w0.z * q0.z + w0.w * q0.w +
                    w1.x * q1.x + w1.y * q1.y + w1.z * q1.z + w1.w * q1.w;
#pragma unroll
        for (int m = 1; m < 64; m <<= 1) acc += __shfl_xor(acc, m);
        if (lane == 0) qpb[b * H + o] = acc + bias[o];
    }
}

// ---------------- K2: 64t x 512o per block; score + sigmoid + ctx partial, fused.
// v2: double-buffered staging (stage k+1 under MFMA of k, ONE barrier/step)
//     + XOR-swizzled Bs (pre-swizzled glds source, swizzled read; rule #21)
//     + epilogue constants loaded after the K-loop (reg pressure).
__global__ __launch_bounds__(512, 4) void k2_fused(const float* __restrict__ value,
                                                   const unsigned short* __restrict__ wbf,
                                                   const float* __restrict__ la,
                                                   const float* __restrict__ conv_w,
                                                   const float* __restrict__ conv_b,
                                                   const float* __restrict__ s_w,
                                                   const float* __restrict__ qpb,
                                                   const float* __restrict__ s_b,
                                                   float* __restrict__ pre_sg,
                                                   float* __restrict__ ctx_num,
                                                   float* __restrict__ denom) {
    __shared__ __align__(16) unsigned short As[2][BT2 * APAD];   // 2 x 5 KB, padded
    __shared__ __align__(16) unsigned short Bs[2][H * 32];       // 2 x 32 KB, glds layout
    __shared__ float las[BT2 + 2];
    __shared__ float redp[BT2][9];                               // padded
    __shared__ float sgs[BT2];

    const int t0 = blockIdx.x * BT2;
    const int b  = blockIdx.y;
    const int tid = threadIdx.x;
    const int wave = tid >> 6;        // 0..7
    const int lane = tid & 63;
    const int tx   = lane & 15;
    const int quad = lane >> 4;
    const int wn   = wave * 64;       // this wave's o-strip

    if (tid < BT2 + 2) {
        const int t = t0 + tid - 1;
        las[tid] = (t >= 0 && t < T) ? la[b * T + t] : 0.f;
    }

    floatx4 acc[4][4];
#pragma unroll
    for (int i = 0; i < 4; ++i)
#pragma unroll
        for (int j = 0; j < 4; ++j) acc[i][j] = (floatx4){0.f, 0.f, 0.f, 0.f};

    // A staging: thread -> row tid>>3 (0..63), float-col (tid&7)*4
    const int arow = tid >> 3;
    const int acol = (tid & 7) * 4;
    const float* agp = value + ((size_t)b * T + t0 + arow) * H + acol;

    // B staging via glds: 32 chunks of 16 rows; wave stages chunks w, w+8, w+16, w+24.
    // Source column-block is PRE-SWIZZLED: cb' = (lane&3) ^ ((lane>>3)&3)  == cb ^ ((row>>1)&3)
    // so that the linear glds write realizes the swizzled LDS layout (rule #21).
    const int brow = lane >> 2;                              // row within chunk
    const int bcs  = ((lane & 3) ^ ((lane >> 3) & 3)) * 8;   // swizzled colblock (halfwords)
    const unsigned short* gB = wbf + (size_t)(wave * 16 + brow) * H + bcs;
    const int rsw = (tx >> 1) & 3;                           // read-side XOR (== (row>>1)&3)

    // ---- prologue: stage k=0 into buffer 0; prefetch A rows for k=32,64
    {
#pragma unroll
        for (int c = 0; c < 4; ++c)
            gl_lds16(gB + (size_t)c * 128 * H, &Bs[0][(wave + c * 8) * 512]);
        f32x4 a0 = *(const f32x4*)agp;
        pack8 p;
        p.h = __builtin_convertvector(a0, bf16x4v);
        *(uint2*)&As[0][arow * APAD + acol] = p.u;
    }
    f32x4 avW = *(const f32x4*)(agp + 32);   // to write this step  (k=(t+1)*32)
    f32x4 avP = *(const f32x4*)(agp + 64);   // prefetched          (k=(t+2)*32)
    __syncthreads();                          // drains vmcnt+lgkm: buf0 ready

    // ---- main loop: ONE barrier per K-step, stage t+1 under compute of t
#pragma unroll 2
    for (int t = 0; t < 16; ++t) {
        const int buf = t & 1;

        if (t < 15) {
#pragma unroll
            for (int c = 0; c < 4; ++c)
                gl_lds16(gB + (size_t)c * 128 * H + (t + 1) * 32,
                         &Bs[buf ^ 1][(wave + c * 8) * 512]);
        }
        f32x4 avN = (f32x4){0.f, 0.f, 0.f, 0.f};
        if (t < 13) avN = *(const f32x4*)(agp + (t + 3) * 32);   // depth-2 prefetch

        bf16x8 af[4], bfr[4];
#pragma unroll
        for (int mi = 0; mi < 4; ++mi)
            af[mi] = *(const bf16x8*)&As[buf][(mi * 16 + tx) * APAD + quad * 8];
#pragma unroll
        for (int ni = 0; ni < 4; ++ni)
            bfr[ni] = *(const bf16x8*)&Bs[buf][(wn + ni * 16 + tx) * 32 + ((quad ^ rsw) << 3)];

        if (t < 15) {                         // write A for step t+1 (other buffer)
            pack8 p;
            p.h = __builtin_convertvector(avW, bf16x4v);
            *(uint2*)&As[buf ^ 1][arow * APAD + acol] = p.u;
            avW = avP;
            avP = avN;
        }

#pragma unroll
        for (int mi = 0; mi < 4; ++mi)
#pragma unroll
            for (int ni = 0; ni < 4; ++ni)
                acc[mi][ni] = __builtin_amdgcn_mfma_f32_16x16x32_bf16(
                    af[mi], bfr[ni], acc[mi][ni], 0, 0, 0);

        if (t < 15) __syncthreads();          // buf^1 staged+written, visible next step
    }

    // per-lane epilogue constants (loaded AFTER the loop: keeps loop regs <=128 total)
    float qp4[4], sw4[4], cb4[4], c04[4], c14[4], c24[4];
#pragma unroll
    for (int ni = 0; ni < 4; ++ni) {
        const int ol = wn + ni * 16 + tx;
        qp4[ni] = qpb[b * H + ol];
        sw4[ni] = s_w[ol];
        cb4[ni] = conv_b[ol];
        c04[ni] = conv_w[ol * 3 + 0];
        c14[ni] = conv_w[ol * 3 + 1];
        c24[ni] = conv_w[ol * 3 + 2];
    }

    // epilogue: tanh + s_w reduce over this wave's 64 o
    float sacc[16];
#pragma unroll
    for (int i = 0; i < 16; ++i) sacc[i] = 0.f;
#pragma unroll
    for (int ni = 0; ni < 4; ++ni) {
#pragma unroll
        for (int mi = 0; mi < 4; ++mi)
#pragma unroll
            for (int r = 0; r < 4; ++r) {
                const int tl = mi * 16 + quad * 4 + r;
                const float conv = c04[ni] * las[tl] + c14[ni] * las[tl + 1] +
                                   c24[ni] * las[tl + 2] + cb4[ni];
                const float x = acc[mi][ni][r] + qp4[ni] + conv;
                const float ex = __expf(2.f * x);
                const float th = 1.f - 2.f * __builtin_amdgcn_rcpf(ex + 1.f);
                sacc[mi * 4 + r] += sw4[ni] * th;
            }
    }
#pragma unroll
    for (int i = 0; i < 16; ++i) {
        float v = sacc[i];
        v += __shfl_xor(v, 1);
        v += __shfl_xor(v, 2);
        v += __shfl_xor(v, 4);
        v += __shfl_xor(v, 8);
        if (tx == 0) redp[(i >> 2) * 16 + quad * 4 + (i & 3)][wave] = v;
    }
    __syncthreads();

    // wave 0: score -> sigmoid -> sgs + pre_sg + denom atomic
    if (tid < BT2) {
        float sc = s_b[0];
#pragma unroll
        for (int w = 0; w < 8; ++w) sc += redp[tid][w];
        const float sg = 1.f / (1.f + __expf(-sc));
        sgs[tid] = sg;
        pre_sg[b * T + t0 + tid] = sg;
        float dsum = sg;
#pragma unroll
        for (int m = 1; m < 64; m <<= 1) dsum += __shfl_xor(dsum, m);
        if (tid == 0) atomicAdd(&denom[b], dsum);
    }
    __syncthreads();                  // sgs visible; Bs free for overlay

    // ctx partial: num[h] += sum_t sgs[t]*value[t][h]; Bs overlaid as redc[4][512]
    float* redc = (float*)Bs;
    const int h4 = (tid & 127) * 4;
    const int tp = tid >> 7;          // 0..3
    f32x4 a = {0.f, 0.f, 0.f, 0.f};
    const float* vb = value + ((size_t)b * T + t0) * H + h4;
    for (int t = tp; t < BT2; t += 4) {
        const float w = sgs[t];
        f32x4 v = *(const f32x4*)(vb + (size_t)t * H);
        a.x += w * v.x; a.y += w * v.y; a.z += w * v.z; a.w += w * v.w;
    }
    *(f32x4*)&redc[tp * 512 + h4] = a;
    __syncthreads();
    if (tid < 128) {
        const int h = tid * 4;
        f32x4 r0 = *(const f32x4*)&redc[0 * 512 + h];
        f32x4 r1 = *(const f32x4*)&redc[1 * 512 + h];
        f32x4 r2 = *(const f32x4*)&redc[2 * 512 + h];
        f32x4 r3 = *(const f32x4*)&redc[3 * 512 + h];
        atomicAdd(&ctx_num[b * H + h + 0], r0.x + r1.x + r2.x + r3.x);
        atomicAdd(&ctx_num[b * H + h + 1], r0.y + r1.y + r2.y + r3.y);
        atomicAdd(&ctx_num[b * H + h + 2], r0.z + r1.z + r2.z + r3.z);
        atomicAdd(&ctx_num[b * H + h + 3], r0.w + r1.w + r2.w + r3.w);
    }
}

// ---------------- K3: scale by 1/denom
__global__ __launch_bounds__(256) void k3_scale(const float* __restrict__ pre_sg,
                                                const float* __restrict__ ctx_num,
                                                const float* __restrict__ denom,
                                                float* __restrict__ attn_out,
                                                float* __restrict__ ctx) {
    const int b = blockIdx.x;
    const int tid = threadIdx.x;
    const float inv = 1.f / denom[b];
#pragma unroll
    for (int i = 0; i < 8; ++i) {
        const int t = tid + i * 256;
        attn_out[b * T + t] = pre_sg[b * T + t] * inv;
    }
#pragma unroll
    for (int i = 0; i < 2; ++i) {
        const int h = tid + i * 256;
        ctx[b * H + h] = ctx_num[b * H + h] * inv;
    }
}

extern "C" void kernel_launch(void* const* d_in, const int* in_sizes, int n_in,
                              void* d_out, int out_size, void* d_ws, size_t ws_size,
                              hipStream_t stream) {
    const float* query  = (const float*)d_in[0];
    const float* value  = (const float*)d_in[1];
    const float* la     = (const float*)d_in[2];
    const float* conv_w = (const float*)d_in[3];
    const float* conv_b = (const float*)d_in[4];
    const float* q_w    = (const float*)d_in[5];
    const float* v_w    = (const float*)d_in[6];
    const float* s_w    = (const float*)d_in[7];
    const float* s_b    = (const float*)d_in[8];
    const float* bias   = (const float*)d_in[9];

    float* out  = (float*)d_out;
    float* ctx  = out;            // (B, H)
    float* attn = out + B * H;    // (B, T)

    float* qpb     = (float*)d_ws;                 // B*H
    float* pre_sg  = qpb + B * H;                  // B*T
    float* ctx_num = pre_sg + B * T;               // B*H
    float* denom   = ctx_num + B * H;              // B
    unsigned short* wbf = (unsigned short*)(denom + 64);   // H*H bf16

    k_init<<<289, 256, 0, stream>>>(query, q_w, bias, v_w, qpb, wbf, ctx_num, denom);

    dim3 g2(T / BT2, B);
    k2_fused<<<g2, 512, 0, stream>>>(value, wbf, la, conv_w, conv_b, s_w, qpb, s_b,
                                     pre_sg, ctx_num, denom);

    k3_scale<<<B, 256, 0, stream>>>(pre_sg, ctx_num, denom, attn, ctx);
}

// Round 2
// 274.986 us; speedup vs baseline: 1.0644x; 1.0644x over previous
//
#include <hip/hip_runtime.h>
#include <math.h>

#define B 32
#define T 2048
#define H 512

#define BT2 32             // t rows per k2 block
#define ASTR 520           // padded LDS row stride for A (bf16 elems); 1040B = 16 mod 128 -> conflict-free

typedef __attribute__((ext_vector_type(8))) __bf16 bf16x8;
typedef __attribute__((ext_vector_type(4))) __bf16 bf16x4v;
typedef __attribute__((ext_vector_type(4))) float f32x4;
typedef __attribute__((ext_vector_type(4))) float floatx4;

union pack8 { bf16x4v h; uint2 u; };

// ---------------- K_init: flat grid.
// blocks [0,256): GEMV q-proj (b=blk>>3, s=blk&7)
// blocks [256,288): convert v_w slice -> bf16 in FRAGMENT-ORDERED layout:
//   wbf halfword index = ((strip*4+ni)*16 + k)*512 + lane*8
//   holds v_w[strip*64+ni*16+(lane&15)][k*32+(lane>>4)*8 + j]
//   so k2's B-fragment load is one coalesced 16B/lane global load.
// block 288: zero ctx_num (B*H) and denom (B)
__global__ __launch_bounds__(256) void k_init(const float* __restrict__ query,
                                              const float* __restrict__ q_w,
                                              const float* __restrict__ bias,
                                              const float* __restrict__ v_w,
                                              float* __restrict__ qpb,
                                              unsigned short* __restrict__ wbf,
                                              float* __restrict__ ctx_num,
                                              float* __restrict__ denom) {
    const int blk = blockIdx.x;
    const int tid = threadIdx.x;

    if (blk >= 288) {
        // zero accumulators
#pragma unroll
        for (int i = 0; i < 16; ++i) {
            const int off = tid * 4 + i * 1024;
            *(f32x4*)(ctx_num + off) = (f32x4){0.f, 0.f, 0.f, 0.f};
        }
        if (tid < B) denom[tid] = 0.f;
        return;
    }
    if (blk >= 256) {
        const int c2 = blk - 256;            // 0..31 -> (strip = c2>>2, ni = c2&3)
        const int wv = tid >> 6;
        const int lane = tid & 63;
        const int srow = (c2 >> 2) * 64 + (c2 & 3) * 16 + (lane & 15);
        const int scol0 = (lane >> 4) * 8;
#pragma unroll
        for (int kk = 0; kk < 4; ++kk) {
            const int k = wv * 4 + kk;
            const float* src = v_w + (size_t)srow * H + k * 32 + scol0;
            f32x4 a0 = *(const f32x4*)src;
            f32x4 a1 = *(const f32x4*)(src + 4);
            pack8 p0, p1;
            p0.h = __builtin_convertvector(a0, bf16x4v);
            p1.h = __builtin_convertvector(a1, bf16x4v);
            uint4 u = {p0.u.x, p0.u.y, p1.u.x, p1.u.y};
            *(uint4*)(wbf + ((size_t)c2 * 16 + k) * 512 + lane * 8) = u;
        }
        return;
    }

    const int b = blk >> 3;
    const int s = blk & 7;
    const int wave = tid >> 6;
    const int lane = tid & 63;

    const float* qb = query + (size_t)b * H + lane * 8;
    float4 q0 = *(const float4*)qb;
    float4 q1 = *(const float4*)(qb + 4);

    const int o0 = s * 64 + wave * 16;
#pragma unroll
    for (int i = 0; i < 16; ++i) {
        const int o = o0 + i;
        const float* wr = q_w + (size_t)o * H + lane * 8;
        float4 w0 = *(const float4*)wr;
        float4 w1 = *(const float4*)(wr + 4);
        float acc = w0.x * q0.x + w0.y * q0.y + w0.z * q0.z + w0.w * q0.w +
                    w1.x * q1.x + w1.y * q1.y + w1.z * q1.z + w1.w * q1.w;
#pragma unroll
        for (int m = 1; m < 64; m <<= 1) acc += __shfl_xor(acc, m);
        if (lane == 0) qpb[b * H + o] = acc + bias[o];
    }
}

// ---------------- K2: 32t x 512o per block; score + sigmoid + ctx partial, fused.
// v3: BARRIER-FREE K-loop. A tile (32x512) staged to LDS once (one barrier),
//     B fragments loaded per-wave from fragment-ordered global wbf (L2-resident,
//     fully coalesced). No LDS B, no per-kstep __syncthreads -> no vmcnt(0)
//     drains; compiler pipelines with counted waits; conflict-free A reads.
__global__ __launch_bounds__(512, 4) void k2_fused(const float* __restrict__ value,
                                                   const unsigned short* __restrict__ wbf,
                                                   const float* __restrict__ la,
                                                   const float* __restrict__ conv_w,
                                                   const float* __restrict__ conv_b,
                                                   const float* __restrict__ s_w,
                                                   const float* __restrict__ qpb,
                                                   const float* __restrict__ s_b,
                                                   float* __restrict__ pre_sg,
                                                   float* __restrict__ ctx_num,
                                                   float* __restrict__ denom) {
    __shared__ __align__(16) unsigned short As[BT2 * ASTR];   // 33280 B
    __shared__ float las[BT2 + 2];
    __shared__ float redp[BT2][9];                            // padded
    __shared__ float sgs[BT2];

    const int t0 = blockIdx.x * BT2;
    const int b  = blockIdx.y;
    const int tid = threadIdx.x;
    const int wave = tid >> 6;        // 0..7
    const int lane = tid & 63;
    const int tx   = lane & 15;
    const int quad = lane >> 4;
    const int wn   = wave * 64;       // this wave's o-strip

    if (tid < BT2 + 2) {
        const int t = t0 + tid - 1;
        las[tid] = (t >= 0 && t < T) ? la[b * T + t] : 0.f;
    }

    // ---- stage A tile (32 rows x 512 cols f32 -> bf16), whole K, once
    {
        const int srow = tid >> 4;            // 0..31
        const int scol = (tid & 15) * 8;      // 0..120
        const float* sg = value + ((size_t)b * T + t0 + srow) * H + scol;
        unsigned short* sl = &As[srow * ASTR + scol];
#pragma unroll
        for (int c = 0; c < 4; ++c) {
            f32x4 a0 = *(const f32x4*)(sg + c * 128);
            f32x4 a1 = *(const f32x4*)(sg + c * 128 + 4);
            pack8 p0, p1;
            p0.h = __builtin_convertvector(a0, bf16x4v);
            p1.h = __builtin_convertvector(a1, bf16x4v);
            uint4 u = {p0.u.x, p0.u.y, p1.u.x, p1.u.y};
            *(uint4*)(sl + c * 128) = u;
        }
    }
    __syncthreads();                  // the ONLY barrier before the epilogue

    floatx4 acc[2][4];
#pragma unroll
    for (int i = 0; i < 2; ++i)
#pragma unroll
        for (int j = 0; j < 4; ++j) acc[i][j] = (floatx4){0.f, 0.f, 0.f, 0.f};

    // B fragments: halfword index ((wave*4+ni)*16 + k)*512 + lane*8
    const unsigned short* gB = wbf + (size_t)wave * 32768 + lane * 8;
    const unsigned short* aB = &As[tx * ASTR + quad * 8];

    // ---- barrier-free K-loop
#pragma unroll 4
    for (int k = 0; k < 16; ++k) {
        bf16x8 bfr[4];
#pragma unroll
        for (int ni = 0; ni < 4; ++ni)
            bfr[ni] = *(const bf16x8*)(gB + ni * 8192 + k * 512);
        bf16x8 af[2];
#pragma unroll
        for (int mi = 0; mi < 2; ++mi)
            af[mi] = *(const bf16x8*)(aB + mi * 16 * ASTR + k * 32);
#pragma unroll
        for (int mi = 0; mi < 2; ++mi)
#pragma unroll
            for (int ni = 0; ni < 4; ++ni)
                acc[mi][ni] = __builtin_amdgcn_mfma_f32_16x16x32_bf16(
                    af[mi], bfr[ni], acc[mi][ni], 0, 0, 0);
    }

    // per-lane epilogue constants (loaded after the loop: reg pressure)
    float qp4[4], sw4[4], cb4[4], c04[4], c14[4], c24[4];
#pragma unroll
    for (int ni = 0; ni < 4; ++ni) {
        const int ol = wn + ni * 16 + tx;
        qp4[ni] = qpb[b * H + ol];
        sw4[ni] = s_w[ol];
        cb4[ni] = conv_b[ol];
        c04[ni] = conv_w[ol * 3 + 0];
        c14[ni] = conv_w[ol * 3 + 1];
        c24[ni] = conv_w[ol * 3 + 2];
    }

    // epilogue: tanh + s_w reduce over this wave's 64 o
    float sacc[8];
#pragma unroll
    for (int i = 0; i < 8; ++i) sacc[i] = 0.f;
#pragma unroll
    for (int ni = 0; ni < 4; ++ni) {
#pragma unroll
        for (int mi = 0; mi < 2; ++mi)
#pragma unroll
            for (int r = 0; r < 4; ++r) {
                const int tl = mi * 16 + quad * 4 + r;
                const float conv = c04[ni] * las[tl] + c14[ni] * las[tl + 1] +
                                   c24[ni] * las[tl + 2] + cb4[ni];
                const float x = acc[mi][ni][r] + qp4[ni] + conv;
                const float ex = __expf(2.f * x);
                const float th = 1.f - 2.f * __builtin_amdgcn_rcpf(ex + 1.f);
                sacc[mi * 4 + r] += sw4[ni] * th;
            }
    }
#pragma unroll
    for (int i = 0; i < 8; ++i) {
        float v = sacc[i];
        v += __shfl_xor(v, 1);
        v += __shfl_xor(v, 2);
        v += __shfl_xor(v, 4);
        v += __shfl_xor(v, 8);
        if (tx == 0) redp[(i >> 2) * 16 + quad * 4 + (i & 3)][wave] = v;
    }
    __syncthreads();

    // first 32 threads: score -> sigmoid -> sgs + pre_sg + denom atomic
    if (tid < BT2) {
        float sc = s_b[0];
#pragma unroll
        for (int w = 0; w < 8; ++w) sc += redp[tid][w];
        const float sg = 1.f / (1.f + __expf(-sc));
        sgs[tid] = sg;
        pre_sg[b * T + t0 + tid] = sg;
        float dsum = sg;
#pragma unroll
        for (int m = 1; m < 32; m <<= 1) dsum += __shfl_xor(dsum, m);
        if (tid == 0) atomicAdd(&denom[b], dsum);
    }
    __syncthreads();                  // sgs visible; As free for overlay

    // ctx partial: num[h] += sum_t sgs[t]*value[t][h]; As overlaid as redc[4][512]
    float* redc = (float*)As;
    const int h4 = (tid & 127) * 4;
    const int tp = tid >> 7;          // 0..3
    f32x4 a = {0.f, 0.f, 0.f, 0.f};
    const float* vb = value + ((size_t)b * T + t0) * H + h4;
    for (int t = tp; t < BT2; t += 4) {
        const float w = sgs[t];
        f32x4 v = *(const f32x4*)(vb + (size_t)t * H);
        a.x += w * v.x; a.y += w * v.y; a.z += w * v.z; a.w += w * v.w;
    }
    *(f32x4*)&redc[tp * 512 + h4] = a;
    __syncthreads();
    if (tid < 128) {
        const int h = tid * 4;
        f32x4 r0 = *(const f32x4*)&redc[0 * 512 + h];
        f32x4 r1 = *(const f32x4*)&redc[1 * 512 + h];
        f32x4 r2 = *(const f32x4*)&redc[2 * 512 + h];
        f32x4 r3 = *(const f32x4*)&redc[3 * 512 + h];
        atomicAdd(&ctx_num[b * H + h + 0], r0.x + r1.x + r2.x + r3.x);
        atomicAdd(&ctx_num[b * H + h + 1], r0.y + r1.y + r2.y + r3.y);
        atomicAdd(&ctx_num[b * H + h + 2], r0.z + r1.z + r2.z + r3.z);
        atomicAdd(&ctx_num[b * H + h + 3], r0.w + r1.w + r2.w + r3.w);
    }
}

// ---------------- K3: scale by 1/denom
__global__ __launch_bounds__(256) void k3_scale(const float* __restrict__ pre_sg,
                                                const float* __restrict__ ctx_num,
                                                const float* __restrict__ denom,
                                                float* __restrict__ attn_out,
                                                float* __restrict__ ctx) {
    const int b = blockIdx.x;
    const int tid = threadIdx.x;
    const float inv = 1.f / denom[b];
#pragma unroll
    for (int i = 0; i < 8; ++i) {
        const int t = tid + i * 256;
        attn_out[b * T + t] = pre_sg[b * T + t] * inv;
    }
#pragma unroll
    for (int i = 0; i < 2; ++i) {
        const int h = tid + i * 256;
        ctx[b * H + h] = ctx_num[b * H + h] * inv;
    }
}

extern "C" void kernel_launch(void* const* d_in, const int* in_sizes, int n_in,
                              void* d_out, int out_size, void* d_ws, size_t ws_size,
                              hipStream_t stream) {
    const float* query  = (const float*)d_in[0];
    const float* value  = (const float*)d_in[1];
    const float* la     = (const float*)d_in[2];
    const float* conv_w = (const float*)d_in[3];
    const float* conv_b = (const float*)d_in[4];
    const float* q_w    = (const float*)d_in[5];
    const float* v_w    = (const float*)d_in[6];
    const float* s_w    = (const float*)d_in[7];
    const float* s_b    = (const float*)d_in[8];
    const float* bias   = (const float*)d_in[9];

    float* out  = (float*)d_out;
    float* ctx  = out;            // (B, H)
    float* attn = out + B * H;    // (B, T)

    float* qpb     = (float*)d_ws;                 // B*H
    float* pre_sg  = qpb + B * H;                  // B*T
    float* ctx_num = pre_sg + B * T;               // B*H
    float* denom   = ctx_num + B * H;              // B
    unsigned short* wbf = (unsigned short*)(denom + 64);   // H*H bf16, fragment-ordered

    k_init<<<289, 256, 0, stream>>>(query, q_w, bias, v_w, qpb, wbf, ctx_num, denom);

    dim3 g2(T / BT2, B);
    k2_fused<<<g2, 512, 0, stream>>>(value, wbf, la, conv_w, conv_b, s_w, qpb, s_b,
                                     pre_sg, ctx_num, denom);

    k3_scale<<<B, 256, 0, stream>>>(pre_sg, ctx_num, denom, attn, ctx);
}